// Round 8
// baseline (215.802 us; speedup 1.0000x reference)
//
#include <hip/hip_runtime.h>
#include <math.h>

#define NATOMS 5
#define NEXP 18
#define NBEAD 4
#define EPSV 1e-8f
#define ML2 (0.02f * 0.02f)

typedef float vf4a __attribute__((ext_vector_type(4), aligned(16)));
typedef float vf2u __attribute__((ext_vector_type(2), aligned(4)));

// Pack per (expert,bead): 8 triplets, one 16-bit entry each in an int4.
// entry: oi | oj<<4 | ok<<8 | okflag<<12, offsets premultiplied by 3.
__global__ void pack_tables(const int* __restrict__ trip, const int* __restrict__ valid,
                            int4* __restrict__ ptbl) {
    int c = blockIdx.x * blockDim.x + threadIdx.x;
    if (c < NEXP * NBEAD) {
        unsigned w[4] = {0u, 0u, 0u, 0u};
#pragma unroll
        for (int t = 0; t < 8; t++) {
            int b = c * 8 + t;
            int i = trip[b * 3 + 0], j = trip[b * 3 + 1], k = trip[b * 3 + 2];
            unsigned ok = (i >= 0 && j >= 0 && k >= 0 && valid[b] > 0) ? 1u : 0u;
            unsigned oi = 3u * (unsigned)min(max(i, 0), NATOMS - 1);
            unsigned oj = 3u * (unsigned)min(max(j, 0), NATOMS - 1);
            unsigned ov = 3u * (unsigned)min(max(k, 0), NATOMS - 1);
            unsigned e = oi | (oj << 4) | (ov << 8) | (ok << 12);
            w[t >> 1] |= e << ((t & 1) * 16);
        }
        ptbl[c] = make_int4((int)w[0], (int)w[1], (int)w[2], (int)w[3]);
    }
}

// Per-row loss: atom MSE from registers, angle part via dynamic gathers from
// the thread's PRIVATE LDS slice (stride 33 dwords -> conflict-free banking).
__device__ __forceinline__ float row_loss(const float* __restrict__ T,
                                          const float* __restrict__ P,
                                          unsigned mbits, int4 pk, float* __restrict__ st) {
    float num_a = 0.f, den_a = 0.f;
    unsigned avm2 = 0u;  // validity bit at premultiplied offset 3*a
#pragma unroll
    for (int a = 0; a < 5; a++) {
        unsigned mb = (mbits >> (3 * a)) & 7u;
        float d0 = T[3 * a + 0] - P[3 * a + 0];
        float d1 = T[3 * a + 1] - P[3 * a + 1];
        float d2 = T[3 * a + 2] - P[3 * a + 2];
        float se = (mb & 1u ? d0 * d0 : 0.f) + (mb & 2u ? d1 * d1 : 0.f) +
                   (mb & 4u ? d2 * d2 : 0.f);
        if (mb) { num_a += se; den_a += 1.f; avm2 |= 1u << (3 * a); }
    }
    float res = num_a / (den_a + EPSV);

    // Spill row to private slice: T at [0,15), P at [16,31).
#pragma unroll
    for (int c = 0; c < 15; c++) st[c] = T[c];
#pragma unroll
    for (int c = 0; c < 15; c++) st[16 + c] = P[c];

    unsigned tw0 = (unsigned)pk.x, tw1 = (unsigned)pk.y;
    unsigned tw2 = (unsigned)pk.z, tw3 = (unsigned)pk.w;

    float num_g = 0.f, den_g = 0.f;
#pragma unroll
    for (int t = 0; t < 8; t++) {
        unsigned wrd = (t < 2) ? tw0 : (t < 4) ? tw1 : (t < 6) ? tw2 : tw3;
        unsigned e = (wrd >> ((t & 1) * 16)) & 0xffffu;
        int oi = e & 15, oj = (e >> 4) & 15, ov = (e >> 8) & 15;
        bool wok = ((e >> 12) & 1u) != 0u;

        float tix = st[oi], tiy = st[oi + 1], tiz = st[oi + 2];
        float tjx = st[oj], tjy = st[oj + 1], tjz = st[oj + 2];
        float tkx = st[ov], tky = st[ov + 1], tkz = st[ov + 2];
        float pix = st[16 + oi], piy = st[17 + oi], piz = st[18 + oi];
        float pjx = st[16 + oj], pjy = st[17 + oj], pjz = st[18 + oj];
        float pkx = st[16 + ov], pky = st[17 + ov], pkz = st[18 + ov];

        float v1tx = tix - tjx, v1ty = tiy - tjy, v1tz = tiz - tjz;
        float v2tx = tkx - tjx, v2ty = tky - tjy, v2tz = tkz - tjz;
        float v1px = pix - pjx, v1py = piy - pjy, v1pz = piz - pjz;
        float v2px = pkx - pjx, v2py = pky - pjy, v2pz = pkz - pjz;

        float l1t = fmaf(v1tx, v1tx, fmaf(v1ty, v1ty, v1tz * v1tz));
        float l2t = fmaf(v2tx, v2tx, fmaf(v2ty, v2ty, v2tz * v2tz));
        float l1p = fmaf(v1px, v1px, fmaf(v1py, v1py, v1pz * v1pz));
        float l2p = fmaf(v2px, v2px, fmaf(v2py, v2py, v2pz * v2pz));

        bool okv = wok && ((avm2 >> oi) & 1) && ((avm2 >> oj) & 1) &&
                   ((avm2 >> ov) & 1) && (l1t > ML2) && (l2t > ML2) &&
                   (l1p > ML2) && (l2p > ML2);

        float rt = __builtin_amdgcn_rsqf(fmaxf(l1t, ML2) * fmaxf(l2t, ML2));
        float rp = __builtin_amdgcn_rsqf(fmaxf(l1p, ML2) * fmaxf(l2p, ML2));

        float dott = fmaf(v1tx, v2tx, fmaf(v1ty, v2ty, v1tz * v2tz));
        float dotp = fmaf(v1px, v2px, fmaf(v1py, v2py, v1pz * v2pz));
        float cut = dott * rt;
        float cup = dotp * rp;
        float cost = fminf(fmaxf(cut, -1.f + 1e-6f), 1.f - 1e-6f);
        float cosp = fminf(fmaxf(cup, -1.f + 1e-6f), 1.f - 1e-6f);
        float sint = __builtin_amdgcn_sqrtf(fmaxf(fmaf(-cut, cut, 1.f), 0.f));
        float sinp = __builtin_amdgcn_sqrtf(fmaxf(fmaf(-cup, cup, 1.f), 0.f));

        float dc = cosp - cost, dsn = sinp - sint;
        if (okv) { num_g += fmaf(dc, dc, dsn * dsn); den_g += 1.f; }
    }
    return res + num_g / (den_g + EPSV);
}

// 4 consecutive rows per thread (group = 240 B = 15 ALIGNED 16B chunks, zero
// line splits), all loads nt (L1 bypass), issued before any consumption:
// 45 dwordx4 in flight per thread. One wave per block -> fully barrier-free.
// LDS: 64 * 33 * 4 = 8448 B. launch_bounds(64,2) allows 256 VGPR (no spill
// for the ~180-reg live set).
__global__ __launch_bounds__(64, 2) void loss_kernel(
    const float* __restrict__ xin, const float* __restrict__ y_true,
    const float* __restrict__ y_pred, const float* __restrict__ mask,
    const int4* __restrict__ ptbl, float* __restrict__ partial, int n) {
    __shared__ float scr[64 * 33];

    const int tid = threadIdx.x;
    const int base = blockIdx.x * 256 + tid * 4;  // n%4==0 -> all-or-none guard
    float* st = scr + tid * 33;  // bank = (tid+o)%32 -> spread across lanes

    float result = 0.f;
    if (base < n) {
        const size_t gb = (size_t)base * 15;  // base%4==0 -> 240B-aligned
        const vf4a* qT = (const vf4a*)(y_true + gb);
        const vf4a* qP = (const vf4a*)(y_pred + gb);
        const vf4a* qM = (const vf4a*)(mask + gb);

        // ---- issue ALL loads up front (aligned nt dwordx4) ----
        float T[60], P[60];
        vf4a Mv[15];
#pragma unroll
        for (int k = 0; k < 15; k++) {
            vf4a t = __builtin_nontemporal_load(qT + k);
            T[4 * k + 0] = t.x; T[4 * k + 1] = t.y; T[4 * k + 2] = t.z; T[4 * k + 3] = t.w;
        }
#pragma unroll
        for (int k = 0; k < 15; k++) {
            vf4a p = __builtin_nontemporal_load(qP + k);
            P[4 * k + 0] = p.x; P[4 * k + 1] = p.y; P[4 * k + 2] = p.z; P[4 * k + 3] = p.w;
        }
#pragma unroll
        for (int k = 0; k < 15; k++) Mv[k] = __builtin_nontemporal_load(qM + k);

        vf2u gbv[4];
#pragma unroll
        for (int r = 0; r < 4; r++)
            gbv[r] = __builtin_nontemporal_load(
                (const vf2u*)(xin + (size_t)(base + r) * 38 + 36));

        // ---- fold M into 4 row bitmasks (frees the M registers) ----
        unsigned mb[4] = {0u, 0u, 0u, 0u};
#pragma unroll
        for (int k = 0; k < 15; k++) {
#pragma unroll
            for (int c = 0; c < 4; c++) {
                int e = 4 * k + c;         // compile-time constants
                int r = e / 15, p = e - r * 15;
                float m = (c == 0) ? Mv[k].x : (c == 1) ? Mv[k].y : (c == 2) ? Mv[k].z
                                                                             : Mv[k].w;
                mb[r] |= (m > 0.f ? 1u : 0u) << p;
            }
        }

        // ---- gate decode + table fetch (tiny, cached) ----
        int4 pk[4];
#pragma unroll
        for (int r = 0; r < 4; r++) {
            float beadf = isfinite(gbv[r].x) ? gbv[r].x : 0.f;
            float gatef = isfinite(gbv[r].y) ? gbv[r].y : 0.f;
            gatef = fminf(fmaxf(gatef, -1e6f), 1e6f);
            beadf = fminf(fmaxf(beadf, -1e6f), 1e6f);
            int rid = min(max((int)rintf(gatef) - 1, 0), NEXP - 1);
            int bid = min(max((int)rintf(beadf), 0), NBEAD - 1);
            pk[r] = ptbl[rid * NBEAD + bid];
        }

        // ---- per-row compute (reuses the one LDS slice) ----
#pragma unroll
        for (int r = 0; r < 4; r++)
            result += row_loss(T + 15 * r, P + 15 * r, mb[r], pk[r], st);
    }

    // ---- wave reduction: block == wave, no barrier anywhere ----
#pragma unroll
    for (int off = 32; off > 0; off >>= 1)
        result += __shfl_down(result, off, 64);
    if (tid == 0) partial[blockIdx.x] = result;
}

__global__ __launch_bounds__(256) void reduce_kernel(const float* __restrict__ partial,
                                                     float* __restrict__ out, int nblocks,
                                                     float inv_n) {
    __shared__ float red[4];
    float s = 0.f;
    for (int i = threadIdx.x; i < nblocks; i += 256) s += partial[i];
#pragma unroll
    for (int off = 32; off > 0; off >>= 1) s += __shfl_down(s, off, 64);
    int lane = threadIdx.x & 63, wv = threadIdx.x >> 6;
    if (lane == 0) red[wv] = s;
    __syncthreads();
    if (threadIdx.x == 0) out[0] = (red[0] + red[1] + red[2] + red[3]) * inv_n;
}

extern "C" void kernel_launch(void* const* d_in, const int* in_sizes, int n_in,
                              void* d_out, int out_size, void* d_ws, size_t ws_size,
                              hipStream_t stream) {
    const float* x = (const float*)d_in[0];
    const float* y_true = (const float*)d_in[1];
    const float* y_pred = (const float*)d_in[2];
    const float* mask = (const float*)d_in[3];
    const int* trip = (const int*)d_in[4];
    const int* valid = (const int*)d_in[5];
    float* out = (float*)d_out;

    int4* ptbl = (int4*)d_ws;                       // 72 * 16 B
    float* partial = (float*)((char*)d_ws + 4096);  // block partials

    const int n = in_sizes[1] / 15;  // N rows (y_true is N x 15)
    const int blocks = (n + 255) / 256;             // 256 rows per 64-thread block

    pack_tables<<<1, 128, 0, stream>>>(trip, valid, ptbl);
    loss_kernel<<<blocks, 64, 0, stream>>>(x, y_true, y_pred, mask, ptbl, partial, n);
    reduce_kernel<<<1, 256, 0, stream>>>(partial, out, blocks, 1.0f / (float)n);
}

// Round 9
// 186.990 us; speedup vs baseline: 1.1541x; 1.1541x over previous
//
#include <hip/hip_runtime.h>
#include <math.h>

#define NATOMS 5
#define NEXP 18
#define NBEAD 4
#define EPSV 1e-8f
#define ML2 (0.02f * 0.02f)

typedef float vf4a __attribute__((ext_vector_type(4), aligned(16)));
typedef float vf2u __attribute__((ext_vector_type(2), aligned(4)));

// Pack per (expert,bead): 8 triplets, one 16-bit entry each in an int4.
// entry: oi | oj<<4 | ok<<8 | okflag<<12, offsets premultiplied by 3.
__global__ void pack_tables(const int* __restrict__ trip, const int* __restrict__ valid,
                            int4* __restrict__ ptbl) {
    int c = blockIdx.x * blockDim.x + threadIdx.x;
    if (c < NEXP * NBEAD) {
        unsigned w[4] = {0u, 0u, 0u, 0u};
#pragma unroll
        for (int t = 0; t < 8; t++) {
            int b = c * 8 + t;
            int i = trip[b * 3 + 0], j = trip[b * 3 + 1], k = trip[b * 3 + 2];
            unsigned ok = (i >= 0 && j >= 0 && k >= 0 && valid[b] > 0) ? 1u : 0u;
            unsigned oi = 3u * (unsigned)min(max(i, 0), NATOMS - 1);
            unsigned oj = 3u * (unsigned)min(max(j, 0), NATOMS - 1);
            unsigned ov = 3u * (unsigned)min(max(k, 0), NATOMS - 1);
            unsigned e = oi | (oj << 4) | (ov << 8) | (ok << 12);
            w[t >> 1] |= e << ((t & 1) * 16);
        }
        ptbl[c] = make_int4((int)w[0], (int)w[1], (int)w[2], (int)w[3]);
    }
}

// One wave per block, 64 rows per wave. Coalesced NT (L1-bypass) staging into
// LDS: per array 240 aligned dwordx4 chunks, lane-consecutive -> 16 lines per
// instruction, zero splits, full line utilization. __syncthreads on a 1-wave
// block is immediately satisfied (no cross-wave coupling).
// LDS: 3 * 960 * 4 = 11520 B -> 13 wave-blocks/CU.
__global__ __launch_bounds__(64) void loss_kernel(
    const float* __restrict__ xin, const float* __restrict__ y_true,
    const float* __restrict__ y_pred, const float* __restrict__ mask,
    const int4* __restrict__ ptbl, float* __restrict__ partial, int n) {
    __shared__ float sT[960];  // 64 rows x 15
    __shared__ float sP[960];
    __shared__ float sM[960];

    const int tid = threadIdx.x;  // 0..63
    const int rbase = blockIdx.x * 64;
    const int row = rbase + tid;
    const size_t dbase = (size_t)rbase * 15;      // dword offset, 3840B-aligned
    const long long total = (long long)n * 15;

    // ---- gate pair first: scattered 1-line-per-lane gather, worst latency ----
    vf2u gb;
    gb.x = 0.f; gb.y = 0.f;
    if (row < n) gb = __builtin_nontemporal_load((const vf2u*)(xin + (size_t)row * 38 + 36));

    // ---- coalesced NT bulk loads: chunk q = k*64+tid, lane-consecutive ----
    const vf4a* qT = (const vf4a*)(y_true + dbase);
    const vf4a* qP = (const vf4a*)(y_pred + dbase);
    const vf4a* qM = (const vf4a*)(mask + dbase);
    vf4a tC[4], pC[4], mC[4];
    bool ok[4];
#pragma unroll
    for (int k = 0; k < 4; k++) {
        int q = k * 64 + tid;
        ok[k] = (q < 240) && (dbase + 4 * (long long)q + 4 <= total);
        if (ok[k]) {
            tC[k] = __builtin_nontemporal_load(qT + q);
            pC[k] = __builtin_nontemporal_load(qP + q);
            mC[k] = __builtin_nontemporal_load(qM + q);
        }
    }
#pragma unroll
    for (int k = 0; k < 4; k++) {
        int q = k * 64 + tid;
        if (ok[k]) {
            ((vf4a*)sT)[q] = tC[k];
            ((vf4a*)sP)[q] = pC[k];
            ((vf4a*)sM)[q] = mC[k];
        }
    }
    __syncthreads();  // 1-wave block: trivial

    float result = 0.f;
    if (row < n) {
        const float* st = sT + tid * 15;  // stride 15 -> 2-way bank alias = free
        const float* sp = sP + tid * 15;
        const float* sm = sM + tid * 15;

        // ---- mask bits (binary mask -> exact) ----
        unsigned mrow = 0u;
#pragma unroll
        for (int c = 0; c < 15; c++) mrow |= (sm[c] > 0.f ? 1u : 0u) << c;

        // ---- atom MSE ----
        float num_a = 0.f, den_a = 0.f;
        unsigned avm2 = 0u;  // validity bit at premultiplied offset 3*a
#pragma unroll
        for (int a = 0; a < 5; a++) {
            unsigned mb = (mrow >> (3 * a)) & 7u;
            float d0 = st[3 * a + 0] - sp[3 * a + 0];
            float d1 = st[3 * a + 1] - sp[3 * a + 1];
            float d2 = st[3 * a + 2] - sp[3 * a + 2];
            float se = (mb & 1u ? d0 * d0 : 0.f) + (mb & 2u ? d1 * d1 : 0.f) +
                       (mb & 4u ? d2 * d2 : 0.f);
            if (mb) { num_a += se; den_a += 1.f; avm2 |= 1u << (3 * a); }
        }
        result = num_a / (den_a + EPSV);

        // ---- gate decode + table fetch (tiny, cached) ----
        float beadf = isfinite(gb.x) ? gb.x : 0.f;
        float gatef = isfinite(gb.y) ? gb.y : 0.f;
        gatef = fminf(fmaxf(gatef, -1e6f), 1e6f);
        beadf = fminf(fmaxf(beadf, -1e6f), 1e6f);
        int rid = min(max((int)rintf(gatef) - 1, 0), NEXP - 1);
        int bid = min(max((int)rintf(beadf), 0), NBEAD - 1);
        int4 pk = ptbl[rid * NBEAD + bid];
        unsigned tw0 = (unsigned)pk.x, tw1 = (unsigned)pk.y;
        unsigned tw2 = (unsigned)pk.z, tw3 = (unsigned)pk.w;

        // ---- angle part: dynamic gathers from own LDS row ----
        float num_g = 0.f, den_g = 0.f;
#pragma unroll
        for (int t = 0; t < 8; t++) {
            unsigned wrd = (t < 2) ? tw0 : (t < 4) ? tw1 : (t < 6) ? tw2 : tw3;
            unsigned e = (wrd >> ((t & 1) * 16)) & 0xffffu;
            int oi = e & 15, oj = (e >> 4) & 15, ov = (e >> 8) & 15;
            bool wok = ((e >> 12) & 1u) != 0u;

            float tix = st[oi], tiy = st[oi + 1], tiz = st[oi + 2];
            float tjx = st[oj], tjy = st[oj + 1], tjz = st[oj + 2];
            float tkx = st[ov], tky = st[ov + 1], tkz = st[ov + 2];
            float pix = sp[oi], piy = sp[oi + 1], piz = sp[oi + 2];
            float pjx = sp[oj], pjy = sp[oj + 1], pjz = sp[oj + 2];
            float pkx = sp[ov], pky = sp[ov + 1], pkz = sp[ov + 2];

            float v1tx = tix - tjx, v1ty = tiy - tjy, v1tz = tiz - tjz;
            float v2tx = tkx - tjx, v2ty = tky - tjy, v2tz = tkz - tjz;
            float v1px = pix - pjx, v1py = piy - pjy, v1pz = piz - pjz;
            float v2px = pkx - pjx, v2py = pky - pjy, v2pz = pkz - pjz;

            float l1t = fmaf(v1tx, v1tx, fmaf(v1ty, v1ty, v1tz * v1tz));
            float l2t = fmaf(v2tx, v2tx, fmaf(v2ty, v2ty, v2tz * v2tz));
            float l1p = fmaf(v1px, v1px, fmaf(v1py, v1py, v1pz * v1pz));
            float l2p = fmaf(v2px, v2px, fmaf(v2py, v2py, v2pz * v2pz));

            bool okv = wok && ((avm2 >> oi) & 1) && ((avm2 >> oj) & 1) &&
                       ((avm2 >> ov) & 1) && (l1t > ML2) && (l2t > ML2) &&
                       (l1p > ML2) && (l2p > ML2);

            float rt = __builtin_amdgcn_rsqf(fmaxf(l1t, ML2) * fmaxf(l2t, ML2));
            float rp = __builtin_amdgcn_rsqf(fmaxf(l1p, ML2) * fmaxf(l2p, ML2));

            float dott = fmaf(v1tx, v2tx, fmaf(v1ty, v2ty, v1tz * v2tz));
            float dotp = fmaf(v1px, v2px, fmaf(v1py, v2py, v1pz * v2pz));
            float cut = dott * rt;
            float cup = dotp * rp;
            float cost = fminf(fmaxf(cut, -1.f + 1e-6f), 1.f - 1e-6f);
            float cosp = fminf(fmaxf(cup, -1.f + 1e-6f), 1.f - 1e-6f);
            float sint = __builtin_amdgcn_sqrtf(fmaxf(fmaf(-cut, cut, 1.f), 0.f));
            float sinp = __builtin_amdgcn_sqrtf(fmaxf(fmaf(-cup, cup, 1.f), 0.f));

            float dc = cosp - cost, dsn = sinp - sint;
            if (okv) { num_g += fmaf(dc, dc, dsn * dsn); den_g += 1.f; }
        }
        result += num_g / (den_g + EPSV);
    }

    // ---- wave reduction: block == wave ----
#pragma unroll
    for (int off = 32; off > 0; off >>= 1)
        result += __shfl_down(result, off, 64);
    if (tid == 0) partial[blockIdx.x] = result;
}

__global__ __launch_bounds__(256) void reduce_kernel(const float* __restrict__ partial,
                                                     float* __restrict__ out, int nblocks,
                                                     float inv_n) {
    __shared__ float red[4];
    float s = 0.f;
    for (int i = threadIdx.x; i < nblocks; i += 256) s += partial[i];
#pragma unroll
    for (int off = 32; off > 0; off >>= 1) s += __shfl_down(s, off, 64);
    int lane = threadIdx.x & 63, wv = threadIdx.x >> 6;
    if (lane == 0) red[wv] = s;
    __syncthreads();
    if (threadIdx.x == 0) out[0] = (red[0] + red[1] + red[2] + red[3]) * inv_n;
}

extern "C" void kernel_launch(void* const* d_in, const int* in_sizes, int n_in,
                              void* d_out, int out_size, void* d_ws, size_t ws_size,
                              hipStream_t stream) {
    const float* x = (const float*)d_in[0];
    const float* y_true = (const float*)d_in[1];
    const float* y_pred = (const float*)d_in[2];
    const float* mask = (const float*)d_in[3];
    const int* trip = (const int*)d_in[4];
    const int* valid = (const int*)d_in[5];
    float* out = (float*)d_out;

    int4* ptbl = (int4*)d_ws;                       // 72 * 16 B
    float* partial = (float*)((char*)d_ws + 4096);  // block partials (~31.3 KB)

    const int n = in_sizes[1] / 15;  // N rows (y_true is N x 15)
    const int blocks = (n + 63) / 64;  // 64 rows per 1-wave block

    pack_tables<<<1, 128, 0, stream>>>(trip, valid, ptbl);
    loss_kernel<<<blocks, 64, 0, stream>>>(x, y_true, y_pred, mask, ptbl, partial, n);
    reduce_kernel<<<1, 256, 0, stream>>>(partial, out, blocks, 1.0f / (float)n);
}

// Round 10
// 181.830 us; speedup vs baseline: 1.1868x; 1.0284x over previous
//
#include <hip/hip_runtime.h>
#include <math.h>

#define NATOMS 5
#define NEXP 18
#define NBEAD 4
#define EPSV 1e-8f
#define ML2 (0.02f * 0.02f)

typedef float vf4a __attribute__((ext_vector_type(4), aligned(16)));
typedef float vf2u __attribute__((ext_vector_type(2), aligned(4)));

#define NBLOCKS 512         // 2 per CU
#define NWAVES (NBLOCKS * 4)

// Pack per (expert,bead): 8 triplets, one 16-bit entry each in an int4.
// entry: oi | oj<<4 | ok<<8 | okflag<<12, offsets premultiplied by 3.
__global__ void pack_tables(const int* __restrict__ trip, const int* __restrict__ valid,
                            int4* __restrict__ ptbl) {
    int c = blockIdx.x * blockDim.x + threadIdx.x;
    if (c < NEXP * NBEAD) {
        unsigned w[4] = {0u, 0u, 0u, 0u};
#pragma unroll
        for (int t = 0; t < 8; t++) {
            int b = c * 8 + t;
            int i = trip[b * 3 + 0], j = trip[b * 3 + 1], k = trip[b * 3 + 2];
            unsigned ok = (i >= 0 && j >= 0 && k >= 0 && valid[b] > 0) ? 1u : 0u;
            unsigned oi = 3u * (unsigned)min(max(i, 0), NATOMS - 1);
            unsigned oj = 3u * (unsigned)min(max(j, 0), NATOMS - 1);
            unsigned ov = 3u * (unsigned)min(max(k, 0), NATOMS - 1);
            unsigned e = oi | (oj << 4) | (ov << 8) | (ok << 12);
            w[t >> 1] |= e << ((t & 1) * 16);
        }
        ptbl[c] = make_int4((int)w[0], (int)w[1], (int)w[2], (int)w[3]);
    }
}

// Issue one tile's loads (64 rows = 240 aligned dwordx4 per array) + gate pair.
__device__ __forceinline__ void load_tile(int t, int lane, long long totald, int n,
                                          const float* __restrict__ y_true,
                                          const float* __restrict__ y_pred,
                                          const float* __restrict__ mask,
                                          const float* __restrict__ xin,
                                          vf4a* __restrict__ bT, vf4a* __restrict__ bP,
                                          vf4a* __restrict__ bM, vf2u& g) {
    const long long dbase = (long long)t * 960;
    const int row = t * 64 + lane;
    if (row < n) g = __builtin_nontemporal_load((const vf2u*)(xin + (size_t)row * 38 + 36));
    const vf4a* qT = (const vf4a*)(y_true + dbase);
    const vf4a* qP = (const vf4a*)(y_pred + dbase);
    const vf4a* qM = (const vf4a*)(mask + dbase);
#pragma unroll
    for (int k = 0; k < 4; k++) {
        int q = k * 64 + lane;
        if (q < 240 && dbase + 4 * (long long)q + 4 <= totald) {
            bT[k] = __builtin_nontemporal_load(qT + q);
            bP[k] = __builtin_nontemporal_load(qP + q);
            bM[k] = __builtin_nontemporal_load(qM + q);
        }
    }
}

// Persistent 4-wave blocks, wave-private LDS tiles, zero barriers.
// Steady-state pipeline per wave: ds_write tile t (frees regs) -> issue tile
// t+stride NT loads into same regs -> compute tile t from LDS.
// LDS: 3 * 4 * 960 * 4 = 46080 B -> 2 blocks/CU. launch_bounds(256,2): <=256 VGPR.
__global__ __launch_bounds__(256, 2) void loss_kernel(
    const float* __restrict__ xin, const float* __restrict__ y_true,
    const float* __restrict__ y_pred, const float* __restrict__ mask,
    const int4* __restrict__ ptbl, float* __restrict__ partial, int n, int ntiles) {
    __shared__ float sT[4][960];
    __shared__ float sP[4][960];
    __shared__ float sM[4][960];

    const int tid = threadIdx.x;
    const int lane = tid & 63;
    const int wv = tid >> 6;
    const int wgid = blockIdx.x * 4 + wv;       // global wave id
    const long long totald = (long long)n * 15;
    float* wT = sT[wv];
    float* wP = sP[wv];
    float* wM = sM[wv];

    float result = 0.f;
    vf4a bT[4], bP[4], bM[4];
    vf2u g;
    g.x = 0.f; g.y = 0.f;

    int t = wgid;
    if (t < ntiles)
        load_tile(t, lane, totald, n, y_true, y_pred, mask, xin, bT, bP, bM, g);

    for (; t < ntiles; t += NWAVES) {
        // ---- stage current tile to wave-private LDS (waits its own vmcnt) ----
#pragma unroll
        for (int k = 0; k < 4; k++) {
            int q = k * 64 + lane;
            if (q < 240 && (long long)t * 960 + 4 * (long long)q + 4 <= totald) {
                ((vf4a*)wT)[q] = bT[k];
                ((vf4a*)wP)[q] = bP[k];
                ((vf4a*)wM)[q] = bM[k];
            }
        }
        const vf2u gcur = g;
        const int row = t * 64 + lane;

        // ---- issue NEXT tile's loads into the just-freed registers ----
        int tn = t + NWAVES;
        if (tn < ntiles)
            load_tile(tn, lane, totald, n, y_true, y_pred, mask, xin, bT, bP, bM, g);

        // ---- compute current tile (reads own-wave LDS; in-order wave => safe) ----
        if (row < n) {
            const float* st = wT + lane * 15;  // stride 15 -> 2-way bank alias = free
            const float* sp = wP + lane * 15;
            const float* sm = wM + lane * 15;

            unsigned mrow = 0u;
#pragma unroll
            for (int c = 0; c < 15; c++) mrow |= (sm[c] > 0.f ? 1u : 0u) << c;

            float num_a = 0.f, den_a = 0.f;
            unsigned avm2 = 0u;  // validity bit at premultiplied offset 3*a
#pragma unroll
            for (int a = 0; a < 5; a++) {
                unsigned mb = (mrow >> (3 * a)) & 7u;
                float d0 = st[3 * a + 0] - sp[3 * a + 0];
                float d1 = st[3 * a + 1] - sp[3 * a + 1];
                float d2 = st[3 * a + 2] - sp[3 * a + 2];
                float se = (mb & 1u ? d0 * d0 : 0.f) + (mb & 2u ? d1 * d1 : 0.f) +
                           (mb & 4u ? d2 * d2 : 0.f);
                if (mb) { num_a += se; den_a += 1.f; avm2 |= 1u << (3 * a); }
            }
            result += num_a / (den_a + EPSV);

            float beadf = isfinite(gcur.x) ? gcur.x : 0.f;
            float gatef = isfinite(gcur.y) ? gcur.y : 0.f;
            gatef = fminf(fmaxf(gatef, -1e6f), 1e6f);
            beadf = fminf(fmaxf(beadf, -1e6f), 1e6f);
            int rid = min(max((int)rintf(gatef) - 1, 0), NEXP - 1);
            int bid = min(max((int)rintf(beadf), 0), NBEAD - 1);
            int4 pk = ptbl[rid * NBEAD + bid];
            unsigned tw0 = (unsigned)pk.x, tw1 = (unsigned)pk.y;
            unsigned tw2 = (unsigned)pk.z, tw3 = (unsigned)pk.w;

            float num_g = 0.f, den_g = 0.f;
#pragma unroll
            for (int tt = 0; tt < 8; tt++) {
                unsigned wrd = (tt < 2) ? tw0 : (tt < 4) ? tw1 : (tt < 6) ? tw2 : tw3;
                unsigned e = (wrd >> ((tt & 1) * 16)) & 0xffffu;
                int oi = e & 15, oj = (e >> 4) & 15, ov = (e >> 8) & 15;
                bool wok = ((e >> 12) & 1u) != 0u;

                float tix = st[oi], tiy = st[oi + 1], tiz = st[oi + 2];
                float tjx = st[oj], tjy = st[oj + 1], tjz = st[oj + 2];
                float tkx = st[ov], tky = st[ov + 1], tkz = st[ov + 2];
                float pix = sp[oi], piy = sp[oi + 1], piz = sp[oi + 2];
                float pjx = sp[oj], pjy = sp[oj + 1], pjz = sp[oj + 2];
                float pkx = sp[ov], pky = sp[ov + 1], pkz = sp[ov + 2];

                float v1tx = tix - tjx, v1ty = tiy - tjy, v1tz = tiz - tjz;
                float v2tx = tkx - tjx, v2ty = tky - tjy, v2tz = tkz - tjz;
                float v1px = pix - pjx, v1py = piy - pjy, v1pz = piz - pjz;
                float v2px = pkx - pjx, v2py = pky - pjy, v2pz = pkz - pjz;

                float l1t = fmaf(v1tx, v1tx, fmaf(v1ty, v1ty, v1tz * v1tz));
                float l2t = fmaf(v2tx, v2tx, fmaf(v2ty, v2ty, v2tz * v2tz));
                float l1p = fmaf(v1px, v1px, fmaf(v1py, v1py, v1pz * v1pz));
                float l2p = fmaf(v2px, v2px, fmaf(v2py, v2py, v2pz * v2pz));

                bool okv = wok && ((avm2 >> oi) & 1) && ((avm2 >> oj) & 1) &&
                           ((avm2 >> ov) & 1) && (l1t > ML2) && (l2t > ML2) &&
                           (l1p > ML2) && (l2p > ML2);

                float rt = __builtin_amdgcn_rsqf(fmaxf(l1t, ML2) * fmaxf(l2t, ML2));
                float rp = __builtin_amdgcn_rsqf(fmaxf(l1p, ML2) * fmaxf(l2p, ML2));

                float dott = fmaf(v1tx, v2tx, fmaf(v1ty, v2ty, v1tz * v2tz));
                float dotp = fmaf(v1px, v2px, fmaf(v1py, v2py, v1pz * v2pz));
                float cut = dott * rt;
                float cup = dotp * rp;
                float cost = fminf(fmaxf(cut, -1.f + 1e-6f), 1.f - 1e-6f);
                float cosp = fminf(fmaxf(cup, -1.f + 1e-6f), 1.f - 1e-6f);
                float sint = __builtin_amdgcn_sqrtf(fmaxf(fmaf(-cut, cut, 1.f), 0.f));
                float sinp = __builtin_amdgcn_sqrtf(fmaxf(fmaf(-cup, cup, 1.f), 0.f));

                float dc = cosp - cost, dsn = sinp - sint;
                if (okv) { num_g += fmaf(dc, dc, dsn * dsn); den_g += 1.f; }
            }
            result += num_g / (den_g + EPSV);
        }
    }

    // ---- wave reduction; one slot per global wave, no barrier ----
#pragma unroll
    for (int off = 32; off > 0; off >>= 1)
        result += __shfl_down(result, off, 64);
    if (lane == 0) partial[wgid] = result;
}

__global__ __launch_bounds__(256) void reduce_kernel(const float* __restrict__ partial,
                                                     float* __restrict__ out, int m,
                                                     float inv_n) {
    __shared__ float red[4];
    float s = 0.f;
    for (int i = threadIdx.x; i < m; i += 256) s += partial[i];
#pragma unroll
    for (int off = 32; off > 0; off >>= 1) s += __shfl_down(s, off, 64);
    int lane = threadIdx.x & 63, wv = threadIdx.x >> 6;
    if (lane == 0) red[wv] = s;
    __syncthreads();
    if (threadIdx.x == 0) out[0] = (red[0] + red[1] + red[2] + red[3]) * inv_n;
}

extern "C" void kernel_launch(void* const* d_in, const int* in_sizes, int n_in,
                              void* d_out, int out_size, void* d_ws, size_t ws_size,
                              hipStream_t stream) {
    const float* x = (const float*)d_in[0];
    const float* y_true = (const float*)d_in[1];
    const float* y_pred = (const float*)d_in[2];
    const float* mask = (const float*)d_in[3];
    const int* trip = (const int*)d_in[4];
    const int* valid = (const int*)d_in[5];
    float* out = (float*)d_out;

    int4* ptbl = (int4*)d_ws;                       // 72 * 16 B
    float* partial = (float*)((char*)d_ws + 4096);  // NWAVES floats

    const int n = in_sizes[1] / 15;  // N rows (y_true is N x 15)
    const int ntiles = (n + 63) / 64;

    pack_tables<<<1, 128, 0, stream>>>(trip, valid, ptbl);
    loss_kernel<<<NBLOCKS, 256, 0, stream>>>(x, y_true, y_pred, mask, ptbl, partial, n,
                                             ntiles);
    reduce_kernel<<<1, 256, 0, stream>>>(partial, out, NWAVES, 1.0f / (float)n);
}